// Round 8
// baseline (5700.584 us; speedup 1.0000x reference)
//
#include <hip/hip_runtime.h>

#define EPS_BN 1e-5f

typedef unsigned int u32;
typedef short short8 __attribute__((ext_vector_type(8)));
typedef float f32x16 __attribute__((ext_vector_type(16)));

constexpr int N_IN_C  = 100000;
constexpr int N_OUT_C = 400000;
constexpr int KTAPS   = 27;
constexpr int M_UP_C  = 100000;
constexpr int M_C_C   = 120000;

constexpr int OTILE   = 128;                    // phase-B rows per block
constexpr int NTILES  = N_OUT_C / OTILE;        // 3125
constexpr int NWIN_U  = (N_IN_C  + 255) / 256;  // 391
constexpr int NWIN_C  = (N_OUT_C + 511) / 512;  // 782
constexpr int NBA_U   = NWIN_U * KTAPS;         // 10557
constexpr int NBA_C   = NWIN_C * KTAPS;         // 21114
constexpr int MAXPAIR = KTAPS * M_C_C;          // 3.24M  (< 2^22)
constexpr int ENTCAP  = MAXPAIR + NBA_C * 31;   // padded A-entries cap

__device__ inline unsigned short f2bf(float f) {
    u32 u = __builtin_bit_cast(u32, f);
    return (unsigned short)((u + 0x7FFFu + ((u >> 16) & 1u)) >> 16);
}
__device__ inline float bf2f(unsigned short u) {
    return __builtin_bit_cast(float, (u32)u << 16);
}

// ---------------------------------------------------------------------------
// Pack weights into MFMA B-fragment layout, bf16.
// frag[tap][f][lane][j] = W[tap][k = 16f + 8*(lane>>5) + j][lane&31]
// ---------------------------------------------------------------------------
__global__ __launch_bounds__(256) void wpack_kernel(
    const float* __restrict__ wU, const float* __restrict__ w1,
    const float* __restrict__ w2,
    ushort* __restrict__ fU, ushort* __restrict__ f1, ushort* __restrict__ f2)
{
    const int t = blockIdx.x * 256 + threadIdx.x;
    const float* w; ushort* dst; int CIN, NF, local;
    if      (t <  6912) { w = wU; dst = fU; CIN = 64; NF = 4; local = t; }
    else if (t < 13824) { w = w1; dst = f1; CIN = 64; NF = 4; local = t - 6912; }
    else if (t < 17280) { w = w2; dst = f2; CIN = 32; NF = 2; local = t - 13824; }
    else return;
    const int lane = local & 63;
    const int fi   = (local >> 6) % NF;
    const int tap  = local / (64 * NF);
    const int half = lane >> 5, colc = lane & 31;
    ushort* o = dst + ((size_t)(tap * NF + fi) * 64 + lane) * 8;
#pragma unroll
    for (int j = 0; j < 8; ++j) {
        const int k = 16 * fi + 8 * half + j;
        o[j] = f2bf(w[((size_t)tap * CIN + k) * 32 + colc]);
    }
}

// ---------------------------------------------------------------------------
// Fused dual histogram: B-buckets = output ROW o; A-buckets = (in>>SH)*27+k.
// (u32 atomics -> native, never the bottleneck.)
// ---------------------------------------------------------------------------
template <int SH>
__global__ __launch_bounds__(256) void histAB_kernel(
    const int* __restrict__ out_idx, const int* __restrict__ in_idx,
    u32* __restrict__ cntB, u32* __restrict__ cntA, int M)
{
    const int k = blockIdx.y;
    const int m = blockIdx.x * 256 + threadIdx.x;
    if (m >= M) return;
    const int o  = out_idx[(size_t)k * M + m];
    const int in = in_idx[(size_t)k * M + m];
    atomicAdd(&cntB[o], 1u);
    atomicAdd(&cntA[(in >> SH) * KTAPS + k], 1u);
}

// ---------------------------------------------------------------------------
// Single-block exclusive scan; PAD32 rounds each bucket up to a 32-multiple.
// ---------------------------------------------------------------------------
template <bool PAD32>
__global__ __launch_bounds__(1024) void scan_kernel(
    const u32* __restrict__ cnt, u32* __restrict__ starts,
    u32* __restrict__ cursor, int nb)
{
    __shared__ u32 part[1024];
    const int t = threadIdx.x;
    const int per = (nb + 1023) >> 10;
    const int b0 = min(t * per, nb);
    const int b1 = min(b0 + per, nb);
    u32 s = 0;
    for (int i = b0; i < b1; ++i)
        s += PAD32 ? ((cnt[i] + 31u) & ~31u) : cnt[i];
    part[t] = s;
    __syncthreads();
    for (int off = 1; off < 1024; off <<= 1) {
        const u32 v = (t >= off) ? part[t - off] : 0u;
        __syncthreads();
        part[t] += v;
        __syncthreads();
    }
    u32 run = t ? part[t - 1] : 0u;
    for (int i = b0; i < b1; ++i) {
        starts[i] = run; cursor[i] = run;
        run += PAD32 ? ((cnt[i] + 31u) & ~31u) : cnt[i];
    }
    if (t == 1023) starts[nb] = run;
}

// ---------------------------------------------------------------------------
// Fused fill: B-rank (by output row) gives pos; A-entry = (in&WINM)<<22 | pos.
// ---------------------------------------------------------------------------
template <int SH, int WINM>
__global__ __launch_bounds__(256) void fillAB_kernel(
    const int* __restrict__ out_idx, const int* __restrict__ in_idx,
    u32* __restrict__ curB, u32* __restrict__ curA,
    u32* __restrict__ entryA, int M)
{
    const int k = blockIdx.y;
    const int m = blockIdx.x * 256 + threadIdx.x;
    if (m >= M) return;
    const int o  = out_idx[(size_t)k * M + m];
    const int in = in_idx[(size_t)k * M + m];
    const u32 pos = atomicAdd(&curB[o], 1u);
    const u32 pA  = atomicAdd(&curA[(in >> SH) * KTAPS + k], 1u);
    entryA[pA] = ((u32)(in & WINM) << 22) | pos;
}

// ---------------------------------------------------------------------------
// Phase A: one block per input window. Stage window rows into LDS (bf16,
// XOR-swizzled 16B chunks), tap-pure MFMA batches gather A-fragments from
// LDS, write each pair's 32-ch bf16 product row to prod[pos] (random 64-B
// store, fire-and-forget; no atomics anywhere).
// ---------------------------------------------------------------------------
template <int NF, int MODE, int WIN>
__global__ __launch_bounds__(256) void phaseA_kernel(
    const void* __restrict__ srcAv, const void* __restrict__ srcBv,
    const ushort* __restrict__ wfrag,
    const u32* __restrict__ entryA, const u32* __restrict__ startsA,
    ushort* __restrict__ prod, int n_src)
{
    constexpr int NCH = NF * 2;        // 16B chunks per row
    constexpr int RPL = 8 / NCH;       // rows per 128B super-row (1 or 2)
    __shared__ ushort win[WIN * NF * 16];

    const int w0   = blockIdx.x * WIN;
    const int tid  = threadIdx.x;
    const int lane = tid & 63;
    const int wid  = tid >> 6;
    const int col  = lane & 31;
    const int half = lane >> 5;

    for (int i = tid; i < WIN * NCH; i += 256) {
        const int r  = i / NCH, ch = i % NCH;
        const int row = w0 + r;
        short8 v = {0, 0, 0, 0, 0, 0, 0, 0};
        if (row < n_src) {
            if (MODE == 0) {
                const float* s = (const float*)srcAv + (size_t)row * 64 + ch * 8;
#pragma unroll
                for (int j = 0; j < 8; ++j) v[j] = (short)f2bf(s[j]);
            } else if (MODE == 1) {
                if (ch < 4) {
                    v = *reinterpret_cast<const short8*>(
                        (const ushort*)srcAv + (size_t)row * 32 + ch * 8);
                } else {
                    const float* s = (const float*)srcBv + (size_t)row * 32 + (ch - 4) * 8;
#pragma unroll
                    for (int j = 0; j < 8; ++j) v[j] = (short)f2bf(s[j]);
                }
            } else {
                v = *reinterpret_cast<const short8*>(
                    (const ushort*)srcAv + (size_t)row * 32 + ch * 8);
            }
        }
        const int addr = (r / RPL) * 64 + ((((r % RPL) * NCH + ch) ^ ((r / RPL) & 7)) * 8);
        *reinterpret_cast<short8*>(&win[addr]) = v;
    }
    __syncthreads();

    const short8* wf8 = reinterpret_cast<const short8*>(wfrag);

    for (int tap = wid; tap < KTAPS; tap += 4) {
        short8 bf[NF];
#pragma unroll
        for (int f = 0; f < NF; ++f) bf[f] = wf8[(tap * NF + f) * 64 + lane];

        const int b  = blockIdx.x * KTAPS + tap;
        const int s0 = (int)startsA[b];
        const int s1 = (int)startsA[b + 1];

        for (int bb = s0; bb < s1; bb += 32) {
            const u32 e   = entryA[bb + col];
            const int r   = (int)(e >> 22) & (WIN - 1);
            const u32 pos = e & 0x3FFFFFu;

            short8 af[NF];
#pragma unroll
            for (int f = 0; f < NF; ++f) {
                const int ch   = f * 2 + half;
                const int addr = (r / RPL) * 64 +
                                 ((((r % RPL) * NCH + ch) ^ ((r / RPL) & 7)) * 8);
                af[f] = *reinterpret_cast<const short8*>(&win[addr]);
            }

            f32x16 acc;
#pragma unroll
            for (int rr = 0; rr < 16; ++rr) acc[rr] = 0.f;
#pragma unroll
            for (int f = 0; f < NF; ++f)
                acc = __builtin_amdgcn_mfma_f32_32x32x16_bf16(af[f], bf[f], acc, 0, 0, 0);

#pragma unroll
            for (int rr = 0; rr < 16; ++rr) {
                const int prow = (rr & 3) + 8 * (rr >> 2) + 4 * half;
                const u32 p    = (u32)__shfl((int)pos, prow);
                if (p != 0x3FFFFFu)
                    prod[(size_t)p * 32 + col] = f2bf(acc[rr]);
            }
        }
    }
}

// ---------------------------------------------------------------------------
// Phase B, atomic-free: products are sorted by output row. One block per
// 128 rows; each 32-lane group owns one row (lane = channel), accumulates
// its segment in a register, writes once. BN partials per block, no atomics.
// pstat layout: [64 slots][NTILES]  (slot c = sum, 32+c = sumsq)
// ---------------------------------------------------------------------------
__global__ __launch_bounds__(256) void phaseB_kernel(
    const ushort* __restrict__ prod,
    const u32* __restrict__ startsB,
    float* __restrict__ dest, float* __restrict__ pstat)
{
    const int tile = blockIdx.x;
    const int tid  = threadIdx.x;
    const int grp  = tid >> 5;     // 0..7
    const int c    = tid & 31;
    const int r0   = tile * OTILE;

    float s = 0.f, q = 0.f;
    for (int rr = grp; rr < OTILE; rr += 8) {
        const int row = r0 + rr;
        const int s0 = (int)startsB[row];
        const int s1 = (int)startsB[row + 1];
        float acc = 0.f;
        for (int i = s0; i < s1; ++i)
            acc += bf2f(prod[(size_t)i * 32 + c]);
        dest[(size_t)row * 32 + c] = acc;
        s += acc;
        q = fmaf(acc, acc, q);
    }

    __shared__ float ls[256], lq[256];
    ls[tid] = s; lq[tid] = q;
    __syncthreads();
    if (tid < 32) {
        float ts = 0.f, tq = 0.f;
#pragma unroll
        for (int g = 0; g < 8; ++g) { ts += ls[g * 32 + tid]; tq += lq[g * 32 + tid]; }
        pstat[(size_t)tid * NTILES + tile]        = ts;
        pstat[(size_t)(32 + tid) * NTILES + tile] = tq;
    }
}

// ---------------------------------------------------------------------------
// Reduce per-tile BN partials -> stats[slot] (64 blocks, contiguous reads).
// ---------------------------------------------------------------------------
__global__ __launch_bounds__(256) void reduce_stats_kernel(
    const float* __restrict__ pstat, float* __restrict__ stats)
{
    const int slot = blockIdx.x;
    const float* src = pstat + (size_t)slot * NTILES;
    float s = 0.f;
    for (int i = threadIdx.x; i < NTILES; i += 256) s += src[i];
    __shared__ float ls[256];
    ls[threadIdx.x] = s;
    __syncthreads();
    for (int off = 128; off > 0; off >>= 1) {
        if (threadIdx.x < off) ls[threadIdx.x] += ls[threadIdx.x + off];
        __syncthreads();
    }
    if (threadIdx.x == 0) stats[slot] = ls[0];
}

// ---------------------------------------------------------------------------
// y = relu((x-mean)*rsqrt(var+eps)*g + bt); dst bf16 (intermediate) or f32.
// ---------------------------------------------------------------------------
template <bool BF16OUT>
__global__ __launch_bounds__(256) void bn_relu_kernel(
    const float* __restrict__ h,
    const float* __restrict__ stats,
    const float* __restrict__ g,
    const float* __restrict__ bt,
    void* __restrict__ dst, int n)
{
    const int i = blockIdx.x * 256 + threadIdx.x;
    if (i >= n * 8) return;
    const float4 v = reinterpret_cast<const float4*>(h)[i];
    const int c0 = (i & 7) * 4;
    const float invn = 1.f / (float)n;
    float o[4];
    const float vin[4] = {v.x, v.y, v.z, v.w};
#pragma unroll
    for (int j = 0; j < 4; ++j) {
        const int c   = c0 + j;
        const float m   = stats[c] * invn;
        const float var = fmaxf(stats[32 + c] * invn - m * m, 0.f);
        const float sc  = rsqrtf(var + EPS_BN) * g[c];
        float y = (vin[j] - m) * sc + bt[c];
        o[j] = y > 0.f ? y : 0.f;
    }
    if (BF16OUT) {
        ushort4 w;
        w.x = f2bf(o[0]); w.y = f2bf(o[1]); w.z = f2bf(o[2]); w.w = f2bf(o[3]);
        reinterpret_cast<ushort4*>(dst)[i] = w;
    } else {
        float4 w = {o[0], o[1], o[2], o[3]};
        reinterpret_cast<float4*>(dst)[i] = w;
    }
}

// ---------------------------------------------------------------------------
extern "C" void kernel_launch(void* const* d_in, const int* in_sizes, int n_in,
                              void* d_out, int out_size, void* d_ws, size_t ws_size,
                              hipStream_t stream)
{
    const float* x      = (const float*)d_in[0];
    const float* x_skip = (const float*)d_in[1];
    const float* w_up   = (const float*)d_in[2];
    // d_in[3] = b_up cancels exactly through train-mode BN -> unused.
    const float* g_up   = (const float*)d_in[4];
    const float* bt_up  = (const float*)d_in[5];
    const float* w1     = (const float*)d_in[6];
    const float* g1     = (const float*)d_in[7];
    const float* bt1    = (const float*)d_in[8];
    const float* w2     = (const float*)d_in[9];
    const float* g2     = (const float*)d_in[10];
    const float* bt2    = (const float*)d_in[11];
    const int* up_in    = (const int*)d_in[12];
    const int* up_out   = (const int*)d_in[13];
    const int* c1_in    = (const int*)d_in[14];
    const int* c1_out   = (const int*)d_in[15];
    const int* c2_in    = (const int*)d_in[16];
    const int* c2_out   = (const int*)d_in[17];

    // ---- workspace carve ----
    char* p = (char*)d_ws;
    auto alloc = [&](size_t bytes) { char* r = p; p += (bytes + 255) & ~(size_t)255; return r; };
    ushort* h16    = (ushort*)alloc((size_t)N_OUT_C * 32 * 2);       // 25.6 MB
    ushort* wfU    = (ushort*)alloc(27 * 4 * 64 * 8 * 2);
    ushort* wf1    = (ushort*)alloc(27 * 4 * 64 * 8 * 2);
    ushort* wf2    = (ushort*)alloc(27 * 2 * 64 * 8 * 2);
    float*  stats  = (float*) alloc(192 * 4);
    float*  pstat  = (float*) alloc((size_t)64 * NTILES * 4);        // 0.8 MB
    u32*    cntB   = (u32*)   alloc((size_t)(N_OUT_C + NBA_C) * 4);  // cntB | cntA
    u32*    cntA   = cntB + N_OUT_C;
    u32*    startsB= (u32*)   alloc((size_t)(N_OUT_C + 1) * 4);
    u32*    curB   = (u32*)   alloc((size_t)N_OUT_C * 4);
    u32*    startsA= (u32*)   alloc((size_t)(NBA_C + 1) * 4);
    u32*    curA   = (u32*)   alloc((size_t)NBA_C * 4);
    u32*    entryA = (u32*)   alloc((size_t)ENTCAP * 4);             // 15.6 MB
    ushort* prod   = (ushort*)alloc((size_t)MAXPAIR * 32 * 2);       // 207.4 MB

    float* out = (float*)d_out;
    const dim3 blk(256);
    const dim3 gUp((M_UP_C + 255) / 256, KTAPS);
    const dim3 gC ((M_C_C  + 255) / 256, KTAPS);
    const int bn_blocks = (N_OUT_C * 8 + 255) / 256;

    wpack_kernel<<<(17280 + 255) / 256, blk, 0, stream>>>(w_up, w1, w2, wfU, wf1, wf2);

    // ================= stage 1: up conv (x fp32 64ch) =====================
    hipMemsetAsync(cntB, 0, (size_t)(N_OUT_C + NBA_C) * 4, stream);
    hipMemsetAsync(entryA, 0xFF, (size_t)ENTCAP * 4, stream);
    histAB_kernel<8><<<gUp, blk, 0, stream>>>(up_out, up_in, cntB, cntA, M_UP_C);
    scan_kernel<false><<<1, 1024, 0, stream>>>(cntB, startsB, curB, N_OUT_C);
    scan_kernel<true ><<<1, 1024, 0, stream>>>(cntA, startsA, curA, NBA_U);
    fillAB_kernel<8, 255><<<gUp, blk, 0, stream>>>(up_out, up_in, curB, curA,
                                                   entryA, M_UP_C);
    phaseA_kernel<4, 0, 256><<<NWIN_U, blk, 0, stream>>>(
        x, nullptr, wfU, entryA, startsA, prod, N_IN_C);
    phaseB_kernel<<<NTILES, blk, 0, stream>>>(prod, startsB, out, pstat);
    reduce_stats_kernel<<<64, blk, 0, stream>>>(pstat, stats);
    bn_relu_kernel<true><<<bn_blocks, blk, 0, stream>>>(out, stats, g_up, bt_up, h16, N_OUT_C);

    // ================= stage 2: conv1 (h16 bf16 | x_skip fp32) ============
    hipMemsetAsync(cntB, 0, (size_t)(N_OUT_C + NBA_C) * 4, stream);
    hipMemsetAsync(entryA, 0xFF, (size_t)ENTCAP * 4, stream);
    histAB_kernel<9><<<gC, blk, 0, stream>>>(c1_out, c1_in, cntB, cntA, M_C_C);
    scan_kernel<false><<<1, 1024, 0, stream>>>(cntB, startsB, curB, N_OUT_C);
    scan_kernel<true ><<<1, 1024, 0, stream>>>(cntA, startsA, curA, NBA_C);
    fillAB_kernel<9, 511><<<gC, blk, 0, stream>>>(c1_out, c1_in, curB, curA,
                                                  entryA, M_C_C);
    phaseA_kernel<4, 1, 512><<<NWIN_C, blk, 0, stream>>>(
        h16, x_skip, wf1, entryA, startsA, prod, N_OUT_C);
    phaseB_kernel<<<NTILES, blk, 0, stream>>>(prod, startsB, out, pstat);
    reduce_stats_kernel<<<64, blk, 0, stream>>>(pstat, stats + 64);
    bn_relu_kernel<true><<<bn_blocks, blk, 0, stream>>>(out, stats + 64, g1, bt1, h16, N_OUT_C);

    // ================= stage 3: conv2 (h16 bf16 32ch) =====================
    hipMemsetAsync(cntB, 0, (size_t)(N_OUT_C + NBA_C) * 4, stream);
    hipMemsetAsync(entryA, 0xFF, (size_t)ENTCAP * 4, stream);
    histAB_kernel<9><<<gC, blk, 0, stream>>>(c2_out, c2_in, cntB, cntA, M_C_C);
    scan_kernel<false><<<1, 1024, 0, stream>>>(cntB, startsB, curB, N_OUT_C);
    scan_kernel<true ><<<1, 1024, 0, stream>>>(cntA, startsA, curA, NBA_C);
    fillAB_kernel<9, 511><<<gC, blk, 0, stream>>>(c2_out, c2_in, curB, curA,
                                                  entryA, M_C_C);
    phaseA_kernel<2, 2, 512><<<NWIN_C, blk, 0, stream>>>(
        h16, nullptr, wf2, entryA, startsA, prod, N_OUT_C);
    phaseB_kernel<<<NTILES, blk, 0, stream>>>(prod, startsB, out, pstat);
    reduce_stats_kernel<<<64, blk, 0, stream>>>(pstat, stats + 128);
    bn_relu_kernel<false><<<bn_blocks, blk, 0, stream>>>(out, stats + 128, g2, bt2, out, N_OUT_C);
}

// Round 9
// 2505.614 us; speedup vs baseline: 2.2751x; 2.2751x over previous
//
#include <hip/hip_runtime.h>

#define EPS_BN 1e-5f

typedef unsigned int u32;
typedef short short8 __attribute__((ext_vector_type(8)));
typedef float f32x16 __attribute__((ext_vector_type(16)));

constexpr int N_IN_C  = 100000;
constexpr int N_OUT_C = 400000;
constexpr int KTAPS   = 27;
constexpr int M_UP_C  = 100000;
constexpr int M_C_C   = 120000;

constexpr int OTILE   = 128;                    // phase-B rows per block
constexpr int NTILES  = N_OUT_C / OTILE;        // 3125
constexpr int NWIN_U  = (N_IN_C  + 255) / 256;  // 391
constexpr int NWIN_C  = (N_OUT_C + 511) / 512;  // 782
constexpr int NBA_U   = NWIN_U * KTAPS;         // 10557
constexpr int NBA_C   = NWIN_C * KTAPS;         // 21114
constexpr int MAXPAIR = KTAPS * M_C_C;          // 3.24M  (< 2^22)
constexpr int ENTCAP  = MAXPAIR + NBA_C * 31;   // padded A-entries cap
constexpr int SCHUNK  = 2048;                   // scan elements per block

__device__ inline unsigned short f2bf(float f) {
    u32 u = __builtin_bit_cast(u32, f);
    return (unsigned short)((u + 0x7FFFu + ((u >> 16) & 1u)) >> 16);
}
__device__ inline float bf2f(unsigned short u) {
    return __builtin_bit_cast(float, (u32)u << 16);
}

// ---------------------------------------------------------------------------
// Pack weights into MFMA B-fragment layout, bf16.
// ---------------------------------------------------------------------------
__global__ __launch_bounds__(256) void wpack_kernel(
    const float* __restrict__ wU, const float* __restrict__ w1,
    const float* __restrict__ w2,
    ushort* __restrict__ fU, ushort* __restrict__ f1, ushort* __restrict__ f2)
{
    const int t = blockIdx.x * 256 + threadIdx.x;
    const float* w; ushort* dst; int CIN, NF, local;
    if      (t <  6912) { w = wU; dst = fU; CIN = 64; NF = 4; local = t; }
    else if (t < 13824) { w = w1; dst = f1; CIN = 64; NF = 4; local = t - 6912; }
    else if (t < 17280) { w = w2; dst = f2; CIN = 32; NF = 2; local = t - 13824; }
    else return;
    const int lane = local & 63;
    const int fi   = (local >> 6) % NF;
    const int tap  = local / (64 * NF);
    const int half = lane >> 5, colc = lane & 31;
    ushort* o = dst + ((size_t)(tap * NF + fi) * 64 + lane) * 8;
#pragma unroll
    for (int j = 0; j < 8; ++j) {
        const int k = 16 * fi + 8 * half + j;
        o[j] = f2bf(w[((size_t)tap * CIN + k) * 32 + colc]);
    }
}

// ---------------------------------------------------------------------------
// Fused dual histogram: B-buckets = output ROW; A-buckets = (in>>SH)*27+k.
// ---------------------------------------------------------------------------
template <int SH>
__global__ __launch_bounds__(256) void histAB_kernel(
    const int* __restrict__ out_idx, const int* __restrict__ in_idx,
    u32* __restrict__ cntB, u32* __restrict__ cntA, int M)
{
    const int k = blockIdx.y;
    const int m = blockIdx.x * 256 + threadIdx.x;
    if (m >= M) return;
    const int o  = out_idx[(size_t)k * M + m];
    const int in = in_idx[(size_t)k * M + m];
    atomicAdd(&cntB[o], 1u);
    atomicAdd(&cntA[(in >> SH) * KTAPS + k], 1u);
}

// ---------------------------------------------------------------------------
// Hierarchical exclusive scan: part -> bsum-scan (1 block) -> emit.
// PAD32 rounds each bucket up to a 32-multiple.
// ---------------------------------------------------------------------------
template <bool PAD32>
__global__ __launch_bounds__(256) void scan_part_kernel(
    const u32* __restrict__ cnt, u32* __restrict__ bsum, int nb)
{
    const int i0 = blockIdx.x * SCHUNK + threadIdx.x * 8;
    u32 s = 0;
#pragma unroll
    for (int j = 0; j < 8; ++j) {
        const int i = i0 + j;
        if (i < nb) {
            const u32 c = cnt[i];
            s += PAD32 ? ((c + 31u) & ~31u) : c;
        }
    }
    __shared__ u32 ls[256];
    ls[threadIdx.x] = s;
    __syncthreads();
    for (int off = 128; off > 0; off >>= 1) {
        if (threadIdx.x < off) ls[threadIdx.x] += ls[threadIdx.x + off];
        __syncthreads();
    }
    if (threadIdx.x == 0) bsum[blockIdx.x] = ls[0];
}

__global__ __launch_bounds__(1024) void scan_bsum_kernel(
    u32* __restrict__ bsum, int nblk)
{
    __shared__ u32 tmp[1024];
    const int t = threadIdx.x;
    const u32 v = (t < nblk) ? bsum[t] : 0u;
    tmp[t] = v;
    __syncthreads();
    for (int off = 1; off < 1024; off <<= 1) {
        const u32 u = (t >= off) ? tmp[t - off] : 0u;
        __syncthreads();
        tmp[t] += u;
        __syncthreads();
    }
    if (t < nblk) bsum[t] = tmp[t] - v;   // exclusive
}

template <bool PAD32>
__global__ __launch_bounds__(256) void scan_emit_kernel(
    const u32* __restrict__ cnt, const u32* __restrict__ bsum,
    u32* __restrict__ starts, u32* __restrict__ cursor, int nb)
{
    const int t  = threadIdx.x;
    const int i0 = blockIdx.x * SCHUNK + t * 8;
    u32 vals[8];
    u32 s = 0;
#pragma unroll
    for (int j = 0; j < 8; ++j) {
        const int i = i0 + j;
        u32 c = (i < nb) ? cnt[i] : 0u;
        c = PAD32 ? ((c + 31u) & ~31u) : c;
        vals[j] = c;
        s += c;
    }
    __shared__ u32 ls[256];
    ls[t] = s;
    __syncthreads();
    for (int off = 1; off < 256; off <<= 1) {
        const u32 u = (t >= off) ? ls[t - off] : 0u;
        __syncthreads();
        ls[t] += u;
        __syncthreads();
    }
    u32 run = bsum[blockIdx.x] + ls[t] - s;
#pragma unroll
    for (int j = 0; j < 8; ++j) {
        const int i = i0 + j;
        if (i < nb) { starts[i] = run; cursor[i] = run; }
        run += vals[j];
    }
    if (blockIdx.x == gridDim.x - 1 && t == 255) starts[nb] = run;
}

// ---------------------------------------------------------------------------
// Fused fill: B-rank (by output row) gives pos; A-entry = (in&WINM)<<22 | pos.
// ---------------------------------------------------------------------------
template <int SH, int WINM>
__global__ __launch_bounds__(256) void fillAB_kernel(
    const int* __restrict__ out_idx, const int* __restrict__ in_idx,
    u32* __restrict__ curB, u32* __restrict__ curA,
    u32* __restrict__ entryA, int M)
{
    const int k = blockIdx.y;
    const int m = blockIdx.x * 256 + threadIdx.x;
    if (m >= M) return;
    const int o  = out_idx[(size_t)k * M + m];
    const int in = in_idx[(size_t)k * M + m];
    const u32 pos = atomicAdd(&curB[o], 1u);
    const u32 pA  = atomicAdd(&curA[(in >> SH) * KTAPS + k], 1u);
    entryA[pA] = ((u32)(in & WINM) << 22) | pos;
}

// ---------------------------------------------------------------------------
// Phase A: one block per input window. Stage window rows into LDS (bf16,
// XOR-swizzled 16B chunks), tap-pure MFMA batches gather A-fragments from
// LDS, write each pair's 32-ch bf16 product row to prod[pos].
// ---------------------------------------------------------------------------
template <int NF, int MODE, int WIN>
__global__ __launch_bounds__(256) void phaseA_kernel(
    const void* __restrict__ srcAv, const void* __restrict__ srcBv,
    const ushort* __restrict__ wfrag,
    const u32* __restrict__ entryA, const u32* __restrict__ startsA,
    ushort* __restrict__ prod, int n_src)
{
    constexpr int NCH = NF * 2;        // 16B chunks per row
    constexpr int RPL = 8 / NCH;       // rows per 128B super-row (1 or 2)
    __shared__ ushort win[WIN * NF * 16];

    const int w0   = blockIdx.x * WIN;
    const int tid  = threadIdx.x;
    const int lane = tid & 63;
    const int wid  = tid >> 6;
    const int col  = lane & 31;
    const int half = lane >> 5;

    for (int i = tid; i < WIN * NCH; i += 256) {
        const int r  = i / NCH, ch = i % NCH;
        const int row = w0 + r;
        short8 v = {0, 0, 0, 0, 0, 0, 0, 0};
        if (row < n_src) {
            if (MODE == 0) {
                const float* s = (const float*)srcAv + (size_t)row * 64 + ch * 8;
#pragma unroll
                for (int j = 0; j < 8; ++j) v[j] = (short)f2bf(s[j]);
            } else if (MODE == 1) {
                if (ch < 4) {
                    v = *reinterpret_cast<const short8*>(
                        (const ushort*)srcAv + (size_t)row * 32 + ch * 8);
                } else {
                    const float* s = (const float*)srcBv + (size_t)row * 32 + (ch - 4) * 8;
#pragma unroll
                    for (int j = 0; j < 8; ++j) v[j] = (short)f2bf(s[j]);
                }
            } else {
                v = *reinterpret_cast<const short8*>(
                    (const ushort*)srcAv + (size_t)row * 32 + ch * 8);
            }
        }
        const int addr = (r / RPL) * 64 + ((((r % RPL) * NCH + ch) ^ ((r / RPL) & 7)) * 8);
        *reinterpret_cast<short8*>(&win[addr]) = v;
    }
    __syncthreads();

    const short8* wf8 = reinterpret_cast<const short8*>(wfrag);

    for (int tap = wid; tap < KTAPS; tap += 4) {
        short8 bf[NF];
#pragma unroll
        for (int f = 0; f < NF; ++f) bf[f] = wf8[(tap * NF + f) * 64 + lane];

        const int b  = blockIdx.x * KTAPS + tap;
        const int s0 = (int)startsA[b];
        const int s1 = (int)startsA[b + 1];

        for (int bb = s0; bb < s1; bb += 32) {
            const u32 e   = entryA[bb + col];
            const int r   = (int)(e >> 22) & (WIN - 1);
            const u32 pos = e & 0x3FFFFFu;

            short8 af[NF];
#pragma unroll
            for (int f = 0; f < NF; ++f) {
                const int ch   = f * 2 + half;
                const int addr = (r / RPL) * 64 +
                                 ((((r % RPL) * NCH + ch) ^ ((r / RPL) & 7)) * 8);
                af[f] = *reinterpret_cast<const short8*>(&win[addr]);
            }

            f32x16 acc;
#pragma unroll
            for (int rr = 0; rr < 16; ++rr) acc[rr] = 0.f;
#pragma unroll
            for (int f = 0; f < NF; ++f)
                acc = __builtin_amdgcn_mfma_f32_32x32x16_bf16(af[f], bf[f], acc, 0, 0, 0);

#pragma unroll
            for (int rr = 0; rr < 16; ++rr) {
                const int prow = (rr & 3) + 8 * (rr >> 2) + 4 * half;
                const u32 p    = (u32)__shfl((int)pos, prow);
                if (p != 0x3FFFFFu)
                    prod[(size_t)p * 32 + col] = f2bf(acc[rr]);
            }
        }
    }
}

// ---------------------------------------------------------------------------
// Phase B, atomic-free segmented reduction. 8 lanes per row, short4 loads
// (64B per entry per row), 4 channel-sums in registers, float4 row write.
// pstat layout: [64 slots][NTILES]  (slot c = sum, 32+c = sumsq)
// ---------------------------------------------------------------------------
__global__ __launch_bounds__(256) void phaseB_kernel(
    const ushort* __restrict__ prod,
    const u32* __restrict__ startsB,
    float* __restrict__ dest, float* __restrict__ pstat)
{
    const int tile = blockIdx.x;
    const int tid  = threadIdx.x;
    const int grp  = tid >> 3;     // 0..31 row group
    const int j    = tid & 7;      // channel quad
    const int r0   = tile * OTILE;

    float cs[4] = {0.f, 0.f, 0.f, 0.f};
    float cq[4] = {0.f, 0.f, 0.f, 0.f};
    for (int rr = grp; rr < OTILE; rr += 32) {
        const int row = r0 + rr;
        const int s0 = (int)startsB[row];
        const int s1 = (int)startsB[row + 1];
        float a0 = 0.f, a1 = 0.f, a2 = 0.f, a3 = 0.f;
        for (int i = s0; i < s1; ++i) {
            const short4 v = *reinterpret_cast<const short4*>(&prod[(size_t)i * 32 + j * 4]);
            a0 += bf2f((unsigned short)v.x);
            a1 += bf2f((unsigned short)v.y);
            a2 += bf2f((unsigned short)v.z);
            a3 += bf2f((unsigned short)v.w);
        }
        const float4 w = {a0, a1, a2, a3};
        *reinterpret_cast<float4*>(&dest[(size_t)row * 32 + j * 4]) = w;
        cs[0] += a0; cs[1] += a1; cs[2] += a2; cs[3] += a3;
        cq[0] = fmaf(a0, a0, cq[0]); cq[1] = fmaf(a1, a1, cq[1]);
        cq[2] = fmaf(a2, a2, cq[2]); cq[3] = fmaf(a3, a3, cq[3]);
    }

    __shared__ float ls[32][33], lq[32][33];
#pragma unroll
    for (int jj = 0; jj < 4; ++jj) {
        ls[grp][j * 4 + jj] = cs[jj];
        lq[grp][j * 4 + jj] = cq[jj];
    }
    __syncthreads();
    if (tid < 32) {
        float ts = 0.f, tq = 0.f;
#pragma unroll
        for (int g = 0; g < 32; ++g) { ts += ls[g][tid]; tq += lq[g][tid]; }
        pstat[(size_t)tid * NTILES + tile]        = ts;
        pstat[(size_t)(32 + tid) * NTILES + tile] = tq;
    }
}

// ---------------------------------------------------------------------------
__global__ __launch_bounds__(256) void reduce_stats_kernel(
    const float* __restrict__ pstat, float* __restrict__ stats)
{
    const int slot = blockIdx.x;
    const float* src = pstat + (size_t)slot * NTILES;
    float s = 0.f;
    for (int i = threadIdx.x; i < NTILES; i += 256) s += src[i];
    __shared__ float ls[256];
    ls[threadIdx.x] = s;
    __syncthreads();
    for (int off = 128; off > 0; off >>= 1) {
        if (threadIdx.x < off) ls[threadIdx.x] += ls[threadIdx.x + off];
        __syncthreads();
    }
    if (threadIdx.x == 0) stats[slot] = ls[0];
}

// ---------------------------------------------------------------------------
template <bool BF16OUT>
__global__ __launch_bounds__(256) void bn_relu_kernel(
    const float* __restrict__ h,
    const float* __restrict__ stats,
    const float* __restrict__ g,
    const float* __restrict__ bt,
    void* __restrict__ dst, int n)
{
    const int i = blockIdx.x * 256 + threadIdx.x;
    if (i >= n * 8) return;
    const float4 v = reinterpret_cast<const float4*>(h)[i];
    const int c0 = (i & 7) * 4;
    const float invn = 1.f / (float)n;
    float o[4];
    const float vin[4] = {v.x, v.y, v.z, v.w};
#pragma unroll
    for (int j = 0; j < 4; ++j) {
        const int c   = c0 + j;
        const float m   = stats[c] * invn;
        const float var = fmaxf(stats[32 + c] * invn - m * m, 0.f);
        const float sc  = rsqrtf(var + EPS_BN) * g[c];
        float y = (vin[j] - m) * sc + bt[c];
        o[j] = y > 0.f ? y : 0.f;
    }
    if (BF16OUT) {
        ushort4 w;
        w.x = f2bf(o[0]); w.y = f2bf(o[1]); w.z = f2bf(o[2]); w.w = f2bf(o[3]);
        reinterpret_cast<ushort4*>(dst)[i] = w;
    } else {
        float4 w = {o[0], o[1], o[2], o[3]};
        reinterpret_cast<float4*>(dst)[i] = w;
    }
}

// ---------------------------------------------------------------------------
extern "C" void kernel_launch(void* const* d_in, const int* in_sizes, int n_in,
                              void* d_out, int out_size, void* d_ws, size_t ws_size,
                              hipStream_t stream)
{
    const float* x      = (const float*)d_in[0];
    const float* x_skip = (const float*)d_in[1];
    const float* w_up   = (const float*)d_in[2];
    // d_in[3] = b_up cancels exactly through train-mode BN -> unused.
    const float* g_up   = (const float*)d_in[4];
    const float* bt_up  = (const float*)d_in[5];
    const float* w1     = (const float*)d_in[6];
    const float* g1     = (const float*)d_in[7];
    const float* bt1    = (const float*)d_in[8];
    const float* w2     = (const float*)d_in[9];
    const float* g2     = (const float*)d_in[10];
    const float* bt2    = (const float*)d_in[11];
    const int* up_in    = (const int*)d_in[12];
    const int* up_out   = (const int*)d_in[13];
    const int* c1_in    = (const int*)d_in[14];
    const int* c1_out   = (const int*)d_in[15];
    const int* c2_in    = (const int*)d_in[16];
    const int* c2_out   = (const int*)d_in[17];

    // ---- workspace carve ----
    char* p = (char*)d_ws;
    auto alloc = [&](size_t bytes) { char* r = p; p += (bytes + 255) & ~(size_t)255; return r; };
    ushort* h16    = (ushort*)alloc((size_t)N_OUT_C * 32 * 2);       // 25.6 MB
    ushort* wfU    = (ushort*)alloc(27 * 4 * 64 * 8 * 2);
    ushort* wf1    = (ushort*)alloc(27 * 4 * 64 * 8 * 2);
    ushort* wf2    = (ushort*)alloc(27 * 2 * 64 * 8 * 2);
    float*  stats  = (float*) alloc(192 * 4);
    float*  pstat  = (float*) alloc((size_t)64 * NTILES * 4);        // 0.8 MB
    u32*    bsum   = (u32*)   alloc(1025 * 4);
    u32*    cntB   = (u32*)   alloc((size_t)(N_OUT_C + NBA_C) * 4);  // cntB | cntA
    u32*    cntA   = cntB + N_OUT_C;
    u32*    startsB= (u32*)   alloc((size_t)(N_OUT_C + 1) * 4);
    u32*    curB   = (u32*)   alloc((size_t)N_OUT_C * 4);
    u32*    startsA= (u32*)   alloc((size_t)(NBA_C + 1) * 4);
    u32*    curA   = (u32*)   alloc((size_t)NBA_C * 4);
    u32*    entryA = (u32*)   alloc((size_t)ENTCAP * 4);             // 15.6 MB
    ushort* prod   = (ushort*)alloc((size_t)MAXPAIR * 32 * 2);       // 207.4 MB

    float* out = (float*)d_out;
    const dim3 blk(256);
    const dim3 gUp((M_UP_C + 255) / 256, KTAPS);
    const dim3 gC ((M_C_C  + 255) / 256, KTAPS);
    const int bn_blocks = (N_OUT_C * 8 + 255) / 256;
    const int nblkB   = (N_OUT_C + SCHUNK - 1) / SCHUNK;   // 196
    const int nblkA_U = (NBA_U   + SCHUNK - 1) / SCHUNK;   // 6
    const int nblkA_C = (NBA_C   + SCHUNK - 1) / SCHUNK;   // 11

    wpack_kernel<<<(17280 + 255) / 256, blk, 0, stream>>>(w_up, w1, w2, wfU, wf1, wf2);

    auto scanB = [&]() {
        scan_part_kernel<false><<<nblkB, blk, 0, stream>>>(cntB, bsum, N_OUT_C);
        scan_bsum_kernel<<<1, 1024, 0, stream>>>(bsum, nblkB);
        scan_emit_kernel<false><<<nblkB, blk, 0, stream>>>(cntB, bsum, startsB, curB, N_OUT_C);
    };
    auto scanA = [&](int nba, int nblk) {
        scan_part_kernel<true><<<nblk, blk, 0, stream>>>(cntA, bsum, nba);
        scan_bsum_kernel<<<1, 1024, 0, stream>>>(bsum, nblk);
        scan_emit_kernel<true><<<nblk, blk, 0, stream>>>(cntA, bsum, startsA, curA, nba);
    };

    // ================= stage 1: up conv (x fp32 64ch) =====================
    hipMemsetAsync(cntB, 0, (size_t)(N_OUT_C + NBA_C) * 4, stream);
    hipMemsetAsync(entryA, 0xFF, (size_t)ENTCAP * 4, stream);
    histAB_kernel<8><<<gUp, blk, 0, stream>>>(up_out, up_in, cntB, cntA, M_UP_C);
    scanB();
    scanA(NBA_U, nblkA_U);
    fillAB_kernel<8, 255><<<gUp, blk, 0, stream>>>(up_out, up_in, curB, curA,
                                                   entryA, M_UP_C);
    phaseA_kernel<4, 0, 256><<<NWIN_U, blk, 0, stream>>>(
        x, nullptr, wfU, entryA, startsA, prod, N_IN_C);
    phaseB_kernel<<<NTILES, blk, 0, stream>>>(prod, startsB, out, pstat);
    reduce_stats_kernel<<<64, blk, 0, stream>>>(pstat, stats);
    bn_relu_kernel<true><<<bn_blocks, blk, 0, stream>>>(out, stats, g_up, bt_up, h16, N_OUT_C);

    // ================= stage 2: conv1 (h16 bf16 | x_skip fp32) ============
    hipMemsetAsync(cntB, 0, (size_t)(N_OUT_C + NBA_C) * 4, stream);
    hipMemsetAsync(entryA, 0xFF, (size_t)ENTCAP * 4, stream);
    histAB_kernel<9><<<gC, blk, 0, stream>>>(c1_out, c1_in, cntB, cntA, M_C_C);
    scanB();
    scanA(NBA_C, nblkA_C);
    fillAB_kernel<9, 511><<<gC, blk, 0, stream>>>(c1_out, c1_in, curB, curA,
                                                  entryA, M_C_C);
    phaseA_kernel<4, 1, 512><<<NWIN_C, blk, 0, stream>>>(
        h16, x_skip, wf1, entryA, startsA, prod, N_OUT_C);
    phaseB_kernel<<<NTILES, blk, 0, stream>>>(prod, startsB, out, pstat);
    reduce_stats_kernel<<<64, blk, 0, stream>>>(pstat, stats + 64);
    bn_relu_kernel<true><<<bn_blocks, blk, 0, stream>>>(out, stats + 64, g1, bt1, h16, N_OUT_C);

    // ================= stage 3: conv2 (h16 bf16 32ch) =====================
    hipMemsetAsync(cntB, 0, (size_t)(N_OUT_C + NBA_C) * 4, stream);
    hipMemsetAsync(entryA, 0xFF, (size_t)ENTCAP * 4, stream);
    histAB_kernel<9><<<gC, blk, 0, stream>>>(c2_out, c2_in, cntB, cntA, M_C_C);
    scanB();
    scanA(NBA_C, nblkA_C);
    fillAB_kernel<9, 511><<<gC, blk, 0, stream>>>(c2_out, c2_in, curB, curA,
                                                  entryA, M_C_C);
    phaseA_kernel<2, 2, 512><<<NWIN_C, blk, 0, stream>>>(
        h16, nullptr, wf2, entryA, startsA, prod, N_OUT_C);
    phaseB_kernel<<<NTILES, blk, 0, stream>>>(prod, startsB, out, pstat);
    reduce_stats_kernel<<<64, blk, 0, stream>>>(pstat, stats + 128);
    bn_relu_kernel<false><<<bn_blocks, blk, 0, stream>>>(out, stats + 128, g2, bt2, out, N_OUT_C);
}

// Round 10
// 1796.601 us; speedup vs baseline: 3.1730x; 1.3946x over previous
//
#include <hip/hip_runtime.h>

#define EPS_BN 1e-5f

typedef unsigned int u32;
typedef short short8 __attribute__((ext_vector_type(8)));
typedef float f32x16 __attribute__((ext_vector_type(16)));

constexpr int N_IN_C  = 100000;
constexpr int N_OUT_C = 400000;
constexpr int KTAPS   = 27;
constexpr int M_UP_C  = 100000;
constexpr int M_C_C   = 120000;

constexpr int NWIN_U  = (N_IN_C  + 255) / 256;  // 391 (SH=8, WIN=256)
constexpr int NWIN_C  = (N_OUT_C + 511) / 512;  // 782 (SH=9, WIN=512)
constexpr int NBA_U   = NWIN_U * KTAPS;         // 10557
constexpr int NBA_C   = NWIN_C * KTAPS;         // 21114
constexpr int MAXPAIR = KTAPS * M_C_C;          // 3.24M
constexpr int ENTCAP  = MAXPAIR + NBA_C * 31;   // padded A-entries cap
constexpr int SCHUNK  = 2048;                   // scan elems per block
constexpr int FCH     = 8192;                   // fill pairs per block
constexpr int MAXW    = 800;                    // >= NWIN_C
constexpr int NTILES  = N_OUT_C / 128;          // 3125 stat tiles

__device__ inline unsigned short f2bf(float f) {
    u32 u = __builtin_bit_cast(u32, f);
    return (unsigned short)((u + 0x7FFFu + ((u >> 16) & 1u)) >> 16);
}

// ---------------------------------------------------------------------------
// Pack weights into MFMA B-fragment layout, bf16.
// ---------------------------------------------------------------------------
__global__ __launch_bounds__(256) void wpack_kernel(
    const float* __restrict__ wU, const float* __restrict__ w1,
    const float* __restrict__ w2,
    ushort* __restrict__ fU, ushort* __restrict__ f1, ushort* __restrict__ f2)
{
    const int t = blockIdx.x * 256 + threadIdx.x;
    const float* w; ushort* dst; int CIN, NF, local;
    if      (t <  6912) { w = wU; dst = fU; CIN = 64; NF = 4; local = t; }
    else if (t < 13824) { w = w1; dst = f1; CIN = 64; NF = 4; local = t - 6912; }
    else if (t < 17280) { w = w2; dst = f2; CIN = 32; NF = 2; local = t - 13824; }
    else return;
    const int lane = local & 63;
    const int fi   = (local >> 6) % NF;
    const int tap  = local / (64 * NF);
    const int half = lane >> 5, colc = lane & 31;
    ushort* o = dst + ((size_t)(tap * NF + fi) * 64 + lane) * 8;
#pragma unroll
    for (int j = 0; j < 8; ++j) {
        const int k = 16 * fi + 8 * half + j;
        o[j] = f2bf(w[((size_t)tap * CIN + k) * 32 + colc]);
    }
}

// ---------------------------------------------------------------------------
// A-side histogram only: bucket = (in>>SH)*27 + k. Counters L2-resident.
// ---------------------------------------------------------------------------
template <int SH>
__global__ __launch_bounds__(256) void histA_kernel(
    const int* __restrict__ in_idx, u32* __restrict__ cntA, int M)
{
    const int k = blockIdx.y;
    const int m = blockIdx.x * 256 + threadIdx.x;
    if (m >= M) return;
    atomicAdd(&cntA[(in_idx[(size_t)k * M + m] >> SH) * KTAPS + k], 1u);
}

// ---------------------------------------------------------------------------
// Hierarchical exclusive scan (pad each bucket to 32-multiple).
// ---------------------------------------------------------------------------
__global__ __launch_bounds__(256) void scan_part_kernel(
    const u32* __restrict__ cnt, u32* __restrict__ bsum, int nb)
{
    const int i0 = blockIdx.x * SCHUNK + threadIdx.x * 8;
    u32 s = 0;
#pragma unroll
    for (int j = 0; j < 8; ++j) {
        const int i = i0 + j;
        if (i < nb) s += (cnt[i] + 31u) & ~31u;
    }
    __shared__ u32 ls[256];
    ls[threadIdx.x] = s;
    __syncthreads();
    for (int off = 128; off > 0; off >>= 1) {
        if (threadIdx.x < off) ls[threadIdx.x] += ls[threadIdx.x + off];
        __syncthreads();
    }
    if (threadIdx.x == 0) bsum[blockIdx.x] = ls[0];
}

__global__ __launch_bounds__(1024) void scan_bsum_kernel(
    u32* __restrict__ bsum, int nblk)
{
    __shared__ u32 tmp[1024];
    const int t = threadIdx.x;
    const u32 v = (t < nblk) ? bsum[t] : 0u;
    tmp[t] = v;
    __syncthreads();
    for (int off = 1; off < 1024; off <<= 1) {
        const u32 u = (t >= off) ? tmp[t - off] : 0u;
        __syncthreads();
        tmp[t] += u;
        __syncthreads();
    }
    if (t < nblk) bsum[t] = tmp[t] - v;
}

__global__ __launch_bounds__(256) void scan_emit_kernel(
    const u32* __restrict__ cnt, const u32* __restrict__ bsum,
    u32* __restrict__ starts, u32* __restrict__ cursor, int nb)
{
    const int t  = threadIdx.x;
    const int i0 = blockIdx.x * SCHUNK + t * 8;
    u32 vals[8];
    u32 s = 0;
#pragma unroll
    for (int j = 0; j < 8; ++j) {
        const int i = i0 + j;
        u32 c = (i < nb) ? cnt[i] : 0u;
        c = (c + 31u) & ~31u;
        vals[j] = c;
        s += c;
    }
    __shared__ u32 ls[256];
    ls[t] = s;
    __syncthreads();
    for (int off = 1; off < 256; off <<= 1) {
        const u32 u = (t >= off) ? ls[t - off] : 0u;
        __syncthreads();
        ls[t] += u;
        __syncthreads();
    }
    u32 run = bsum[blockIdx.x] + ls[t] - s;
#pragma unroll
    for (int j = 0; j < 8; ++j) {
        const int i = i0 + j;
        if (i < nb) { starts[i] = run; cursor[i] = run; }
        run += vals[j];
    }
    if (blockIdx.x == gridDim.x - 1 && t == 255) starts[nb] = run;
}

// ---------------------------------------------------------------------------
// Binned fill: per (tap, 8K-chunk) block, LDS counting-sort by window, then
// reserve per-window global ranges (one u32 atomic each) and flush contiguous
// runs -> near-full-line entry writes (kills the 16x write amplification).
// Entry = (in & (WIN-1)) << 19 | out_row.  Sentinel pad stays 0xFFFFFFFF.
// ---------------------------------------------------------------------------
template <int SH>
__global__ __launch_bounds__(256) void fill_binned_kernel(
    const int* __restrict__ in_idx, const int* __restrict__ out_idx,
    u32* __restrict__ curA, u32* __restrict__ entryA, int M, int nwin)
{
    __shared__ u32 hist[MAXW];
    __shared__ u32 lofs[MAXW];    // exclusive offsets, then cursors
    __shared__ u32 gbase[MAXW];
    __shared__ u32 lent[FCH];
    __shared__ u32 psum[256];

    const int k   = blockIdx.y;
    const int m0  = blockIdx.x * FCH;
    const int cnt = min(FCH, M - m0);
    const int t   = threadIdx.x;

    for (int w = t; w < nwin; w += 256) hist[w] = 0;
    __syncthreads();

    const int* ink  = in_idx  + (size_t)k * M + m0;
    const int* outk = out_idx + (size_t)k * M + m0;

    for (int i = t; i < cnt; i += 256)
        atomicAdd(&hist[ink[i] >> SH], 1u);
    __syncthreads();

    // block exclusive scan of hist (4 slots/thread covers MAXW)
    u32 loc[4];
    u32 s = 0;
#pragma unroll
    for (int j = 0; j < 4; ++j) {
        const int w = t * 4 + j;
        const u32 c = (w < nwin) ? hist[w] : 0u;
        loc[j] = s;
        s += c;
    }
    psum[t] = s;
    __syncthreads();
    for (int off = 1; off < 256; off <<= 1) {
        const u32 v = (t >= off) ? psum[t - off] : 0u;
        __syncthreads();
        psum[t] += v;
        __syncthreads();
    }
    const u32 tbase = psum[t] - s;
#pragma unroll
    for (int j = 0; j < 4; ++j) {
        const int w = t * 4 + j;
        if (w < nwin) {
            lofs[w] = tbase + loc[j];
            const u32 c = hist[w];
            if (c) gbase[w] = atomicAdd(&curA[(size_t)w * KTAPS + k], c);
        }
    }
    __syncthreads();

    // pass 2: scatter into LDS-sorted order (lofs doubles as cursor)
    for (int i = t; i < cnt; i += 256) {
        const int in = ink[i];
        const int o  = outk[i];
        const int w  = in >> SH;
        const u32 p  = atomicAdd(&lofs[w], 1u);
        lent[p] = ((u32)(in & ((1 << SH) - 1)) << 19) | (u32)o;
    }
    __syncthreads();

    // flush runs (contiguous per window)
    for (int w = t; w < nwin; w += 256) {
        const u32 c = hist[w];
        if (!c) continue;
        const u32 lo = lofs[w] - c;       // cursor ended at start+c
        const u32 gb = gbase[w];
        for (u32 j = 0; j < c; ++j)
            entryA[gb + j] = lent[lo + j];
    }
}

// ---------------------------------------------------------------------------
// Conv: one block per input window. Stage window rows into LDS (bf16,
// XOR-swizzled 16B chunks); tap-pure MFMA batches gather A-fragments from
// LDS; scatter C elements straight into acc[row*32+col] with HARDWARE fp32
// global atomics (unsafeAtomicAdd -> global_atomic_add_f32, fire-and-forget;
// 32 consecutive lanes = one 128B line per C-row). No prod buffer, no B-sort.
// ---------------------------------------------------------------------------
template <int NF, int MODE, int WIN>
__global__ __launch_bounds__(256) void conv_kernel(
    const void* __restrict__ srcAv, const void* __restrict__ srcBv,
    const ushort* __restrict__ wfrag,
    const u32* __restrict__ entryA, const u32* __restrict__ startsA,
    float* __restrict__ acc, int n_src)
{
    constexpr int NCH = NF * 2;        // 16B chunks per row
    constexpr int RPL = 8 / NCH;       // rows per 128B super-row (1 or 2)
    __shared__ ushort win[WIN * NF * 16];

    const int w0   = blockIdx.x * WIN;
    const int tid  = threadIdx.x;
    const int lane = tid & 63;
    const int wid  = tid >> 6;
    const int col  = lane & 31;
    const int half = lane >> 5;

    for (int i = tid; i < WIN * NCH; i += 256) {
        const int r  = i / NCH, ch = i % NCH;
        const int row = w0 + r;
        short8 v = {0, 0, 0, 0, 0, 0, 0, 0};
        if (row < n_src) {
            if (MODE == 0) {
                const float* sp = (const float*)srcAv + (size_t)row * 64 + ch * 8;
#pragma unroll
                for (int j = 0; j < 8; ++j) v[j] = (short)f2bf(sp[j]);
            } else if (MODE == 1) {
                if (ch < 4) {
                    v = *reinterpret_cast<const short8*>(
                        (const ushort*)srcAv + (size_t)row * 32 + ch * 8);
                } else {
                    const float* sp = (const float*)srcBv + (size_t)row * 32 + (ch - 4) * 8;
#pragma unroll
                    for (int j = 0; j < 8; ++j) v[j] = (short)f2bf(sp[j]);
                }
            } else {
                v = *reinterpret_cast<const short8*>(
                    (const ushort*)srcAv + (size_t)row * 32 + ch * 8);
            }
        }
        const int addr = (r / RPL) * 64 + ((((r % RPL) * NCH + ch) ^ ((r / RPL) & 7)) * 8);
        *reinterpret_cast<short8*>(&win[addr]) = v;
    }
    __syncthreads();

    const short8* wf8 = reinterpret_cast<const short8*>(wfrag);

    for (int tap = wid; tap < KTAPS; tap += 4) {
        short8 bf[NF];
#pragma unroll
        for (int f = 0; f < NF; ++f) bf[f] = wf8[(tap * NF + f) * 64 + lane];

        const int b  = blockIdx.x * KTAPS + tap;
        const int s0 = (int)startsA[b];
        const int s1 = (int)startsA[b + 1];

        for (int bb = s0; bb < s1; bb += 32) {
            const u32 e  = entryA[bb + col];
            const int r  = (int)(e >> 19) & (WIN - 1);
            const int ro = (int)(e & 0x7FFFFu);   // out row; sentinel -> 0x7FFFF

            short8 af[NF];
#pragma unroll
            for (int f = 0; f < NF; ++f) {
                const int ch   = f * 2 + half;
                const int addr = (r / RPL) * 64 +
                                 ((((r % RPL) * NCH + ch) ^ ((r / RPL) & 7)) * 8);
                af[f] = *reinterpret_cast<const short8*>(&win[addr]);
            }

            f32x16 cacc;
#pragma unroll
            for (int rr = 0; rr < 16; ++rr) cacc[rr] = 0.f;
#pragma unroll
            for (int f = 0; f < NF; ++f)
                cacc = __builtin_amdgcn_mfma_f32_32x32x16_bf16(af[f], bf[f], cacc, 0, 0, 0);

#pragma unroll
            for (int rr = 0; rr < 16; ++rr) {
                const int prow = (rr & 3) + 8 * (rr >> 2) + 4 * half;
                const int row  = __shfl(ro, prow);
                if (row != 0x7FFFF)
                    unsafeAtomicAdd(&acc[(size_t)row * 32 + col], cacc[rr]);
            }
        }
    }
}

// ---------------------------------------------------------------------------
// BN partial stats over acc (sequential), then 64-block reduce.
// pstat layout: [64 slots][NTILES]
// ---------------------------------------------------------------------------
__global__ __launch_bounds__(256) void stats_part_kernel(
    const float* __restrict__ acc, float* __restrict__ pstat)
{
    const int tile = blockIdx.x;
    const int tid  = threadIdx.x;
    const int grp  = tid >> 3;
    const int j    = tid & 7;
    float cs[4] = {0.f, 0.f, 0.f, 0.f};
    float cq[4] = {0.f, 0.f, 0.f, 0.f};
    for (int rr = grp; rr < 128; rr += 32) {
        const float4 v = *reinterpret_cast<const float4*>(
            &acc[(size_t)(tile * 128 + rr) * 32 + j * 4]);
        cs[0] += v.x; cs[1] += v.y; cs[2] += v.z; cs[3] += v.w;
        cq[0] = fmaf(v.x, v.x, cq[0]); cq[1] = fmaf(v.y, v.y, cq[1]);
        cq[2] = fmaf(v.z, v.z, cq[2]); cq[3] = fmaf(v.w, v.w, cq[3]);
    }
    __shared__ float ls[32][33], lq[32][33];
#pragma unroll
    for (int jj = 0; jj < 4; ++jj) {
        ls[grp][j * 4 + jj] = cs[jj];
        lq[grp][j * 4 + jj] = cq[jj];
    }
    __syncthreads();
    if (tid < 32) {
        float ts = 0.f, tq = 0.f;
#pragma unroll
        for (int g = 0; g < 32; ++g) { ts += ls[g][tid]; tq += lq[g][tid]; }
        pstat[(size_t)tid * NTILES + tile]        = ts;
        pstat[(size_t)(32 + tid) * NTILES + tile] = tq;
    }
}

__global__ __launch_bounds__(256) void reduce_stats_kernel(
    const float* __restrict__ pstat, float* __restrict__ stats)
{
    const int slot = blockIdx.x;
    const float* src = pstat + (size_t)slot * NTILES;
    float s = 0.f;
    for (int i = threadIdx.x; i < NTILES; i += 256) s += src[i];
    __shared__ float ls[256];
    ls[threadIdx.x] = s;
    __syncthreads();
    for (int off = 128; off > 0; off >>= 1) {
        if (threadIdx.x < off) ls[threadIdx.x] += ls[threadIdx.x + off];
        __syncthreads();
    }
    if (threadIdx.x == 0) stats[slot] = ls[0];
}

// ---------------------------------------------------------------------------
// y = relu((x-mean)*rsqrt(var+eps)*g + bt); dst bf16 (intermediate) or f32.
// ---------------------------------------------------------------------------
template <bool BF16OUT>
__global__ __launch_bounds__(256) void bn_relu_kernel(
    const float* __restrict__ h,
    const float* __restrict__ stats,
    const float* __restrict__ g,
    const float* __restrict__ bt,
    void* __restrict__ dst, int n)
{
    const int i = blockIdx.x * 256 + threadIdx.x;
    if (i >= n * 8) return;
    const float4 v = reinterpret_cast<const float4*>(h)[i];
    const int c0 = (i & 7) * 4;
    const float invn = 1.f / (float)n;
    float o[4];
    const float vin[4] = {v.x, v.y, v.z, v.w};
#pragma unroll
    for (int j = 0; j < 4; ++j) {
        const int c   = c0 + j;
        const float m   = stats[c] * invn;
        const float var = fmaxf(stats[32 + c] * invn - m * m, 0.f);
        const float sc  = rsqrtf(var + EPS_BN) * g[c];
        float y = (vin[j] - m) * sc + bt[c];
        o[j] = y > 0.f ? y : 0.f;
    }
    if (BF16OUT) {
        ushort4 w;
        w.x = f2bf(o[0]); w.y = f2bf(o[1]); w.z = f2bf(o[2]); w.w = f2bf(o[3]);
        reinterpret_cast<ushort4*>(dst)[i] = w;
    } else {
        float4 w = {o[0], o[1], o[2], o[3]};
        reinterpret_cast<float4*>(dst)[i] = w;
    }
}

// ---------------------------------------------------------------------------
extern "C" void kernel_launch(void* const* d_in, const int* in_sizes, int n_in,
                              void* d_out, int out_size, void* d_ws, size_t ws_size,
                              hipStream_t stream)
{
    const float* x      = (const float*)d_in[0];
    const float* x_skip = (const float*)d_in[1];
    const float* w_up   = (const float*)d_in[2];
    // d_in[3] = b_up cancels exactly through train-mode BN -> unused.
    const float* g_up   = (const float*)d_in[4];
    const float* bt_up  = (const float*)d_in[5];
    const float* w1     = (const float*)d_in[6];
    const float* g1     = (const float*)d_in[7];
    const float* bt1    = (const float*)d_in[8];
    const float* w2     = (const float*)d_in[9];
    const float* g2     = (const float*)d_in[10];
    const float* bt2    = (const float*)d_in[11];
    const int* up_in    = (const int*)d_in[12];
    const int* up_out   = (const int*)d_in[13];
    const int* c1_in    = (const int*)d_in[14];
    const int* c1_out   = (const int*)d_in[15];
    const int* c2_in    = (const int*)d_in[16];
    const int* c2_out   = (const int*)d_in[17];

    // ---- workspace carve ----
    char* p = (char*)d_ws;
    auto alloc = [&](size_t bytes) { char* r = p; p += (bytes + 255) & ~(size_t)255; return r; };
    ushort* h16    = (ushort*)alloc((size_t)N_OUT_C * 32 * 2);   // 25.6 MB
    float*  acc    = (float*) alloc((size_t)N_OUT_C * 32 * 4);   // 51.2 MB
    ushort* wfU    = (ushort*)alloc(27 * 4 * 64 * 8 * 2);
    ushort* wf1    = (ushort*)alloc(27 * 4 * 64 * 8 * 2);
    ushort* wf2    = (ushort*)alloc(27 * 2 * 64 * 8 * 2);
    float*  stats  = (float*) alloc(192 * 4);
    float*  pstat  = (float*) alloc((size_t)64 * NTILES * 4);    // 0.8 MB
    u32*    bsum   = (u32*)   alloc(1025 * 4);
    u32*    cntA   = (u32*)   alloc((size_t)NBA_C * 4);
    u32*    startsA= (u32*)   alloc((size_t)(NBA_C + 1) * 4);
    u32*    curA   = (u32*)   alloc((size_t)NBA_C * 4);
    u32*    entryA = (u32*)   alloc((size_t)ENTCAP * 4);         // 13.2 MB

    float* out = (float*)d_out;
    const dim3 blk(256);
    const dim3 gHu((M_UP_C + 255) / 256, KTAPS);
    const dim3 gHc((M_C_C  + 255) / 256, KTAPS);
    const dim3 gFu((M_UP_C + FCH - 1) / FCH, KTAPS);   // 13 x 27
    const dim3 gFc((M_C_C  + FCH - 1) / FCH, KTAPS);   // 15 x 27
    const int bn_blocks = (N_OUT_C * 8 + 255) / 256;
    const int nblkA_U = (NBA_U + SCHUNK - 1) / SCHUNK; // 6
    const int nblkA_C = (NBA_C + SCHUNK - 1) / SCHUNK; // 11
    const size_t accBytes = (size_t)N_OUT_C * 32 * 4;

    wpack_kernel<<<(17280 + 255) / 256, blk, 0, stream>>>(w_up, w1, w2, wfU, wf1, wf2);

    auto scanA = [&](int nba, int nblk) {
        scan_part_kernel<<<nblk, blk, 0, stream>>>(cntA, bsum, nba);
        scan_bsum_kernel<<<1, 1024, 0, stream>>>(bsum, nblk);
        scan_emit_kernel<<<nblk, blk, 0, stream>>>(cntA, bsum, startsA, curA, nba);
    };

    // ================= stage 1: up conv (x fp32 64ch) =====================
    hipMemsetAsync(acc, 0, accBytes, stream);
    hipMemsetAsync(cntA, 0, (size_t)NBA_C * 4, stream);
    hipMemsetAsync(entryA, 0xFF, (size_t)ENTCAP * 4, stream);
    histA_kernel<8><<<gHu, blk, 0, stream>>>(up_in, cntA, M_UP_C);
    scanA(NBA_U, nblkA_U);
    fill_binned_kernel<8><<<gFu, blk, 0, stream>>>(up_in, up_out, curA, entryA,
                                                   M_UP_C, NWIN_U);
    conv_kernel<4, 0, 256><<<NWIN_U, blk, 0, stream>>>(
        x, nullptr, wfU, entryA, startsA, acc, N_IN_C);
    stats_part_kernel<<<NTILES, blk, 0, stream>>>(acc, pstat);
    reduce_stats_kernel<<<64, blk, 0, stream>>>(pstat, stats);
    bn_relu_kernel<true><<<bn_blocks, blk, 0, stream>>>(acc, stats, g_up, bt_up, h16, N_OUT_C);

    // ================= stage 2: conv1 (h16 bf16 | x_skip fp32) ============
    hipMemsetAsync(acc, 0, accBytes, stream);
    hipMemsetAsync(cntA, 0, (size_t)NBA_C * 4, stream);
    hipMemsetAsync(entryA, 0xFF, (size_t)ENTCAP * 4, stream);
    histA_kernel<9><<<gHc, blk, 0, stream>>>(c1_in, cntA, M_C_C);
    scanA(NBA_C, nblkA_C);
    fill_binned_kernel<9><<<gFc, blk, 0, stream>>>(c1_in, c1_out, curA, entryA,
                                                   M_C_C, NWIN_C);
    conv_kernel<4, 1, 512><<<NWIN_C, blk, 0, stream>>>(
        h16, x_skip, wf1, entryA, startsA, acc, N_OUT_C);
    stats_part_kernel<<<NTILES, blk, 0, stream>>>(acc, pstat);
    reduce_stats_kernel<<<64, blk, 0, stream>>>(pstat, stats + 64);
    bn_relu_kernel<true><<<bn_blocks, blk, 0, stream>>>(acc, stats + 64, g1, bt1, h16, N_OUT_C);

    // ================= stage 3: conv2 (h16 bf16 32ch) =====================
    hipMemsetAsync(acc, 0, accBytes, stream);
    hipMemsetAsync(cntA, 0, (size_t)NBA_C * 4, stream);
    hipMemsetAsync(entryA, 0xFF, (size_t)ENTCAP * 4, stream);
    histA_kernel<9><<<gHc, blk, 0, stream>>>(c2_in, cntA, M_C_C);
    scanA(NBA_C, nblkA_C);
    fill_binned_kernel<9><<<gFc, blk, 0, stream>>>(c2_in, c2_out, curA, entryA,
                                                   M_C_C, NWIN_C);
    conv_kernel<2, 2, 512><<<NWIN_C, blk, 0, stream>>>(
        h16, nullptr, wf2, entryA, startsA, acc, N_OUT_C);
    stats_part_kernel<<<NTILES, blk, 0, stream>>>(acc, pstat);
    reduce_stats_kernel<<<64, blk, 0, stream>>>(pstat, stats + 128);
    bn_relu_kernel<false><<<bn_blocks, blk, 0, stream>>>(acc, stats + 128, g2, bt2, out, N_OUT_C);
}

// Round 11
// 1361.766 us; speedup vs baseline: 4.1862x; 1.3193x over previous
//
#include <hip/hip_runtime.h>

#define EPS_BN 1e-5f

typedef unsigned int u32;
typedef short short8 __attribute__((ext_vector_type(8)));
typedef float f32x16 __attribute__((ext_vector_type(16)));
typedef _Float16 h4 __attribute__((ext_vector_type(4)));

constexpr int N_IN_C  = 100000;
constexpr int N_OUT_C = 400000;
constexpr int KTAPS   = 27;
constexpr int M_UP_C  = 100000;
constexpr int M_C_C   = 120000;

constexpr int NWIN_U  = (N_IN_C  + 255) / 256;  // 391 (SH=8, WIN=256)
constexpr int NWIN_C  = (N_OUT_C + 511) / 512;  // 782 (SH=9, WIN=512)
constexpr int NBA_U   = NWIN_U * KTAPS;         // 10557
constexpr int NBA_C   = NWIN_C * KTAPS;         // 21114
constexpr int MAXPAIR = KTAPS * M_C_C;          // 3.24M
constexpr int ENTCAP  = MAXPAIR + NBA_C * 31;   // padded A-entries cap
constexpr int SCHUNK  = 2048;                   // scan elems per block
constexpr int FCH     = 8192;                   // fill pairs per block
constexpr int MAXW    = 800;                    // >= NWIN_C
constexpr int NTILES  = N_OUT_C / 128;          // 3125 stat tiles

__device__ inline unsigned short f2bf(float f) {
    u32 u = __builtin_bit_cast(u32, f);
    return (unsigned short)((u + 0x7FFFu + ((u >> 16) & 1u)) >> 16);
}

// ---------------------------------------------------------------------------
// Pack weights into MFMA B-fragment layout, bf16.
// ---------------------------------------------------------------------------
__global__ __launch_bounds__(256) void wpack_kernel(
    const float* __restrict__ wU, const float* __restrict__ w1,
    const float* __restrict__ w2,
    ushort* __restrict__ fU, ushort* __restrict__ f1, ushort* __restrict__ f2)
{
    const int t = blockIdx.x * 256 + threadIdx.x;
    const float* w; ushort* dst; int CIN, NF, local;
    if      (t <  6912) { w = wU; dst = fU; CIN = 64; NF = 4; local = t; }
    else if (t < 13824) { w = w1; dst = f1; CIN = 64; NF = 4; local = t - 6912; }
    else if (t < 17280) { w = w2; dst = f2; CIN = 32; NF = 2; local = t - 13824; }
    else return;
    const int lane = local & 63;
    const int fi   = (local >> 6) % NF;
    const int tap  = local / (64 * NF);
    const int half = lane >> 5, colc = lane & 31;
    ushort* o = dst + ((size_t)(tap * NF + fi) * 64 + lane) * 8;
#pragma unroll
    for (int j = 0; j < 8; ++j) {
        const int k = 16 * fi + 8 * half + j;
        o[j] = f2bf(w[((size_t)tap * CIN + k) * 32 + colc]);
    }
}

// ---------------------------------------------------------------------------
// A-side histogram: bucket = (in>>SH)*27 + k. Counters L2-resident.
// ---------------------------------------------------------------------------
template <int SH>
__global__ __launch_bounds__(256) void histA_kernel(
    const int* __restrict__ in_idx, u32* __restrict__ cntA, int M)
{
    const int k = blockIdx.y;
    const int m = blockIdx.x * 256 + threadIdx.x;
    if (m >= M) return;
    atomicAdd(&cntA[(in_idx[(size_t)k * M + m] >> SH) * KTAPS + k], 1u);
}

// ---------------------------------------------------------------------------
// Hierarchical exclusive scan (pad each bucket to 32-multiple).
// ---------------------------------------------------------------------------
__global__ __launch_bounds__(256) void scan_part_kernel(
    const u32* __restrict__ cnt, u32* __restrict__ bsum, int nb)
{
    const int i0 = blockIdx.x * SCHUNK + threadIdx.x * 8;
    u32 s = 0;
#pragma unroll
    for (int j = 0; j < 8; ++j) {
        const int i = i0 + j;
        if (i < nb) s += (cnt[i] + 31u) & ~31u;
    }
    __shared__ u32 ls[256];
    ls[threadIdx.x] = s;
    __syncthreads();
    for (int off = 128; off > 0; off >>= 1) {
        if (threadIdx.x < off) ls[threadIdx.x] += ls[threadIdx.x + off];
        __syncthreads();
    }
    if (threadIdx.x == 0) bsum[blockIdx.x] = ls[0];
}

__global__ __launch_bounds__(1024) void scan_bsum_kernel(
    u32* __restrict__ bsum, int nblk)
{
    __shared__ u32 tmp[1024];
    const int t = threadIdx.x;
    const u32 v = (t < nblk) ? bsum[t] : 0u;
    tmp[t] = v;
    __syncthreads();
    for (int off = 1; off < 1024; off <<= 1) {
        const u32 u = (t >= off) ? tmp[t - off] : 0u;
        __syncthreads();
        tmp[t] += u;
        __syncthreads();
    }
    if (t < nblk) bsum[t] = tmp[t] - v;
}

__global__ __launch_bounds__(256) void scan_emit_kernel(
    const u32* __restrict__ cnt, const u32* __restrict__ bsum,
    u32* __restrict__ starts, u32* __restrict__ cursor, int nb)
{
    const int t  = threadIdx.x;
    const int i0 = blockIdx.x * SCHUNK + t * 8;
    u32 vals[8];
    u32 s = 0;
#pragma unroll
    for (int j = 0; j < 8; ++j) {
        const int i = i0 + j;
        u32 c = (i < nb) ? cnt[i] : 0u;
        c = (c + 31u) & ~31u;
        vals[j] = c;
        s += c;
    }
    __shared__ u32 ls[256];
    ls[t] = s;
    __syncthreads();
    for (int off = 1; off < 256; off <<= 1) {
        const u32 u = (t >= off) ? ls[t - off] : 0u;
        __syncthreads();
        ls[t] += u;
        __syncthreads();
    }
    u32 run = bsum[blockIdx.x] + ls[t] - s;
#pragma unroll
    for (int j = 0; j < 8; ++j) {
        const int i = i0 + j;
        if (i < nb) { starts[i] = run; cursor[i] = run; }
        run += vals[j];
    }
    if (blockIdx.x == gridDim.x - 1 && t == 255) starts[nb] = run;
}

// ---------------------------------------------------------------------------
// Binned fill: per (tap, 8K-chunk) block, LDS counting-sort by window, then
// reserve per-window global ranges and flush contiguous runs.
// Entry = (in & (WIN-1)) << 19 | out_row.  Sentinel pad stays 0xFFFFFFFF.
// ---------------------------------------------------------------------------
template <int SH>
__global__ __launch_bounds__(256) void fill_binned_kernel(
    const int* __restrict__ in_idx, const int* __restrict__ out_idx,
    u32* __restrict__ curA, u32* __restrict__ entryA, int M, int nwin)
{
    __shared__ u32 hist[MAXW];
    __shared__ u32 lofs[MAXW];
    __shared__ u32 gbase[MAXW];
    __shared__ u32 lent[FCH];
    __shared__ u32 psum[256];

    const int k   = blockIdx.y;
    const int m0  = blockIdx.x * FCH;
    const int cnt = min(FCH, M - m0);
    const int t   = threadIdx.x;

    for (int w = t; w < nwin; w += 256) hist[w] = 0;
    __syncthreads();

    const int* ink  = in_idx  + (size_t)k * M + m0;
    const int* outk = out_idx + (size_t)k * M + m0;

    for (int i = t; i < cnt; i += 256)
        atomicAdd(&hist[ink[i] >> SH], 1u);
    __syncthreads();

    u32 loc[4];
    u32 s = 0;
#pragma unroll
    for (int j = 0; j < 4; ++j) {
        const int w = t * 4 + j;
        const u32 c = (w < nwin) ? hist[w] : 0u;
        loc[j] = s;
        s += c;
    }
    psum[t] = s;
    __syncthreads();
    for (int off = 1; off < 256; off <<= 1) {
        const u32 v = (t >= off) ? psum[t - off] : 0u;
        __syncthreads();
        psum[t] += v;
        __syncthreads();
    }
    const u32 tbase = psum[t] - s;
#pragma unroll
    for (int j = 0; j < 4; ++j) {
        const int w = t * 4 + j;
        if (w < nwin) {
            lofs[w] = tbase + loc[j];
            const u32 c = hist[w];
            if (c) gbase[w] = atomicAdd(&curA[(size_t)w * KTAPS + k], c);
        }
    }
    __syncthreads();

    for (int i = t; i < cnt; i += 256) {
        const int in = ink[i];
        const int o  = outk[i];
        const int w  = in >> SH;
        const u32 p  = atomicAdd(&lofs[w], 1u);
        lent[p] = ((u32)(in & ((1 << SH) - 1)) << 19) | (u32)o;
    }
    __syncthreads();

    for (int w = t; w < nwin; w += 256) {
        const u32 c = hist[w];
        if (!c) continue;
        const u32 lo = lofs[w] - c;
        const u32 gb = gbase[w];
        for (u32 j = 0; j < c; ++j)
            entryA[gb + j] = lent[lo + j];
    }
}

// ---------------------------------------------------------------------------
// Conv: one block per (input window, tap-half). Stage window rows into LDS
// (bf16, XOR-swizzled); tap-pure MFMA batches gather A-fragments from LDS;
// scatter C into a fp16 accumulator via global_atomic_pk_add_f16 (2 channels
// per 4B atomic -> half the atomic bytes of fp32). Lane pairing: even lanes
// carry reg rr, odd lanes rr+1.
// ---------------------------------------------------------------------------
template <int NF, int MODE, int WIN>
__global__ __launch_bounds__(256) void conv_kernel(
    const void* __restrict__ srcAv, const void* __restrict__ srcBv,
    const ushort* __restrict__ wfrag,
    const u32* __restrict__ entryA, const u32* __restrict__ startsA,
    _Float16* __restrict__ accH, int n_src)
{
    constexpr int NCH = NF * 2;        // 16B chunks per row
    constexpr int RPL = 8 / NCH;       // rows per 128B super-row
    __shared__ ushort win[WIN * NF * 16];

    const int w0   = blockIdx.x * WIN;
    const int tid  = threadIdx.x;
    const int lane = tid & 63;
    const int wid  = tid >> 6;
    const int col  = lane & 31;
    const int half = lane >> 5;

    for (int i = tid; i < WIN * NCH; i += 256) {
        const int r  = i / NCH, ch = i % NCH;
        const int row = w0 + r;
        short8 v = {0, 0, 0, 0, 0, 0, 0, 0};
        if (row < n_src) {
            if (MODE == 0) {
                const float* sp = (const float*)srcAv + (size_t)row * 64 + ch * 8;
#pragma unroll
                for (int j = 0; j < 8; ++j) v[j] = (short)f2bf(sp[j]);
            } else if (MODE == 1) {
                if (ch < 4) {
                    v = *reinterpret_cast<const short8*>(
                        (const ushort*)srcAv + (size_t)row * 32 + ch * 8);
                } else {
                    const float* sp = (const float*)srcBv + (size_t)row * 32 + (ch - 4) * 8;
#pragma unroll
                    for (int j = 0; j < 8; ++j) v[j] = (short)f2bf(sp[j]);
                }
            } else {
                v = *reinterpret_cast<const short8*>(
                    (const ushort*)srcAv + (size_t)row * 32 + ch * 8);
            }
        }
        const int addr = (r / RPL) * 64 + ((((r % RPL) * NCH + ch) ^ ((r / RPL) & 7)) * 8);
        *reinterpret_cast<short8*>(&win[addr]) = v;
    }
    __syncthreads();

    const short8* wf8 = reinterpret_cast<const short8*>(wfrag);

    for (int tap = blockIdx.y * 4 + wid; tap < KTAPS; tap += 8) {
        short8 bf[NF];
#pragma unroll
        for (int f = 0; f < NF; ++f) bf[f] = wf8[(tap * NF + f) * 64 + lane];

        const int b  = blockIdx.x * KTAPS + tap;
        const int s0 = (int)startsA[b];
        const int s1 = (int)startsA[b + 1];

        for (int bb = s0; bb < s1; bb += 32) {
            const u32 e  = entryA[bb + col];
            const int r  = (int)(e >> 19) & (WIN - 1);
            const int ro = (int)(e & 0x7FFFFu);   // out row; sentinel = 0x7FFFF

            short8 af[NF];
#pragma unroll
            for (int f = 0; f < NF; ++f) {
                const int ch   = f * 2 + half;
                const int addr = (r / RPL) * 64 +
                                 ((((r % RPL) * NCH + ch) ^ ((r / RPL) & 7)) * 8);
                af[f] = *reinterpret_cast<const short8*>(&win[addr]);
            }

            f32x16 cacc;
#pragma unroll
            for (int rr = 0; rr < 16; ++rr) cacc[rr] = 0.f;
#pragma unroll
            for (int f = 0; f < NF; ++f)
                cacc = __builtin_amdgcn_mfma_f32_32x32x16_bf16(af[f], bf[f], cacc, 0, 0, 0);

            const bool oddl = lane & 1;
#pragma unroll
            for (int rr = 0; rr < 16; rr += 2) {
                const int pr0  = (rr & 3) + 8 * (rr >> 2) + 4 * half;
                const int pr1  = ((rr + 1) & 3) + 8 * ((rr + 1) >> 2) + 4 * half;
                const int row0 = __shfl(ro, pr0);
                const int row1 = __shfl(ro, pr1);
                const float a  = cacc[rr], bb2 = cacc[rr + 1];
                const float a2 = __shfl_xor(a, 1);
                const float b2 = __shfl_xor(bb2, 1);
                const float lo = oddl ? b2  : a;
                const float hi = oddl ? bb2 : a2;
                const int  row = oddl ? row1 : row0;
                if (row != 0x7FFFF) {
                    const u32 pk = __builtin_bit_cast(u32,
                        __builtin_amdgcn_cvt_pkrtz(lo, hi));
                    void* ap = (char*)accH + ((size_t)row << 6) + ((u32)(col >> 1) << 2);
                    asm volatile("global_atomic_pk_add_f16 %0, %1, off"
                                 :: "v"(ap), "v"(pk) : "memory");
                }
            }
        }
    }
}

// ---------------------------------------------------------------------------
// BN partial stats over fp16 acc, then 64-block reduce.
// ---------------------------------------------------------------------------
__global__ __launch_bounds__(256) void stats_part_kernel(
    const _Float16* __restrict__ accH, float* __restrict__ pstat)
{
    const int tile = blockIdx.x;
    const int tid  = threadIdx.x;
    const int grp  = tid >> 3;
    const int j    = tid & 7;
    float cs[4] = {0.f, 0.f, 0.f, 0.f};
    float cq[4] = {0.f, 0.f, 0.f, 0.f};
    for (int rr = grp; rr < 128; rr += 32) {
        const h4 v = *reinterpret_cast<const h4*>(
            &accH[(size_t)(tile * 128 + rr) * 32 + j * 4]);
#pragma unroll
        for (int jj = 0; jj < 4; ++jj) {
            const float f = (float)v[jj];
            cs[jj] += f;
            cq[jj] = fmaf(f, f, cq[jj]);
        }
    }
    __shared__ float ls[32][33], lq[32][33];
#pragma unroll
    for (int jj = 0; jj < 4; ++jj) {
        ls[grp][j * 4 + jj] = cs[jj];
        lq[grp][j * 4 + jj] = cq[jj];
    }
    __syncthreads();
    if (tid < 32) {
        float ts = 0.f, tq = 0.f;
#pragma unroll
        for (int g = 0; g < 32; ++g) { ts += ls[g][tid]; tq += lq[g][tid]; }
        pstat[(size_t)tid * NTILES + tile]        = ts;
        pstat[(size_t)(32 + tid) * NTILES + tile] = tq;
    }
}

__global__ __launch_bounds__(256) void reduce_stats_kernel(
    const float* __restrict__ pstat, float* __restrict__ stats)
{
    const int slot = blockIdx.x;
    const float* src = pstat + (size_t)slot * NTILES;
    float s = 0.f;
    for (int i = threadIdx.x; i < NTILES; i += 256) s += src[i];
    __shared__ float ls[256];
    ls[threadIdx.x] = s;
    __syncthreads();
    for (int off = 128; off > 0; off >>= 1) {
        if (threadIdx.x < off) ls[threadIdx.x] += ls[threadIdx.x + off];
        __syncthreads();
    }
    if (threadIdx.x == 0) stats[slot] = ls[0];
}

// ---------------------------------------------------------------------------
// y = relu((x-mean)*rsqrt(var+eps)*g + bt) from fp16 acc;
// dst bf16 (intermediate) or f32 (final).
// ---------------------------------------------------------------------------
template <bool BF16OUT>
__global__ __launch_bounds__(256) void bn_relu_kernel(
    const _Float16* __restrict__ hsrc,
    const float* __restrict__ stats,
    const float* __restrict__ g,
    const float* __restrict__ bt,
    void* __restrict__ dst, int n)
{
    const int i = blockIdx.x * 256 + threadIdx.x;
    if (i >= n * 8) return;
    const h4 v = *reinterpret_cast<const h4*>(&hsrc[(size_t)i * 4]);
    const int c0 = (i & 7) * 4;
    const float invn = 1.f / (float)n;
    float o[4];
#pragma unroll
    for (int j = 0; j < 4; ++j) {
        const int c   = c0 + j;
        const float m   = stats[c] * invn;
        const float var = fmaxf(stats[32 + c] * invn - m * m, 0.f);
        const float sc  = rsqrtf(var + EPS_BN) * g[c];
        float y = ((float)v[j] - m) * sc + bt[c];
        o[j] = y > 0.f ? y : 0.f;
    }
    if (BF16OUT) {
        ushort4 w;
        w.x = f2bf(o[0]); w.y = f2bf(o[1]); w.z = f2bf(o[2]); w.w = f2bf(o[3]);
        reinterpret_cast<ushort4*>(dst)[i] = w;
    } else {
        float4 w = {o[0], o[1], o[2], o[3]};
        reinterpret_cast<float4*>(dst)[i] = w;
    }
}

// ---------------------------------------------------------------------------
extern "C" void kernel_launch(void* const* d_in, const int* in_sizes, int n_in,
                              void* d_out, int out_size, void* d_ws, size_t ws_size,
                              hipStream_t stream)
{
    const float* x      = (const float*)d_in[0];
    const float* x_skip = (const float*)d_in[1];
    const float* w_up   = (const float*)d_in[2];
    // d_in[3] = b_up cancels exactly through train-mode BN -> unused.
    const float* g_up   = (const float*)d_in[4];
    const float* bt_up  = (const float*)d_in[5];
    const float* w1     = (const float*)d_in[6];
    const float* g1     = (const float*)d_in[7];
    const float* bt1    = (const float*)d_in[8];
    const float* w2     = (const float*)d_in[9];
    const float* g2     = (const float*)d_in[10];
    const float* bt2    = (const float*)d_in[11];
    const int* up_in    = (const int*)d_in[12];
    const int* up_out   = (const int*)d_in[13];
    const int* c1_in    = (const int*)d_in[14];
    const int* c1_out   = (const int*)d_in[15];
    const int* c2_in    = (const int*)d_in[16];
    const int* c2_out   = (const int*)d_in[17];

    // ---- workspace carve ----
    char* p = (char*)d_ws;
    auto alloc = [&](size_t bytes) { char* r = p; p += (bytes + 255) & ~(size_t)255; return r; };
    ushort*    h16    = (ushort*)   alloc((size_t)N_OUT_C * 32 * 2);   // 25.6 MB
    _Float16*  accH   = (_Float16*) alloc((size_t)N_OUT_C * 32 * 2);   // 25.6 MB
    ushort*    wfU    = (ushort*)   alloc(27 * 4 * 64 * 8 * 2);
    ushort*    wf1    = (ushort*)   alloc(27 * 4 * 64 * 8 * 2);
    ushort*    wf2    = (ushort*)   alloc(27 * 2 * 64 * 8 * 2);
    float*     stats  = (float*)    alloc(192 * 4);
    float*     pstat  = (float*)    alloc((size_t)64 * NTILES * 4);    // 0.8 MB
    u32*       bsum   = (u32*)      alloc(1025 * 4);
    u32*       cntA   = (u32*)      alloc((size_t)NBA_C * 4);
    u32*       startsA= (u32*)      alloc((size_t)(NBA_C + 1) * 4);
    u32*       curA   = (u32*)      alloc((size_t)NBA_C * 4);
    u32*       entryA = (u32*)      alloc((size_t)ENTCAP * 4);         // 13.2 MB

    float* out = (float*)d_out;
    const dim3 blk(256);
    const dim3 gHu((M_UP_C + 255) / 256, KTAPS);
    const dim3 gHc((M_C_C  + 255) / 256, KTAPS);
    const dim3 gFu((M_UP_C + FCH - 1) / FCH, KTAPS);
    const dim3 gFc((M_C_C  + FCH - 1) / FCH, KTAPS);
    const int bn_blocks = (N_OUT_C * 8 + 255) / 256;
    const int nblkA_U = (NBA_U + SCHUNK - 1) / SCHUNK;
    const int nblkA_C = (NBA_C + SCHUNK - 1) / SCHUNK;
    const size_t accBytes = (size_t)N_OUT_C * 32 * 2;

    wpack_kernel<<<(17280 + 255) / 256, blk, 0, stream>>>(w_up, w1, w2, wfU, wf1, wf2);

    auto scanA = [&](int nba, int nblk) {
        scan_part_kernel<<<nblk, blk, 0, stream>>>(cntA, bsum, nba);
        scan_bsum_kernel<<<1, 1024, 0, stream>>>(bsum, nblk);
        scan_emit_kernel<<<nblk, blk, 0, stream>>>(cntA, bsum, startsA, curA, nba);
    };

    // ================= stage 1: up conv (x fp32 64ch) =====================
    hipMemsetAsync(accH, 0, accBytes, stream);
    hipMemsetAsync(cntA, 0, (size_t)NBA_C * 4, stream);
    hipMemsetAsync(entryA, 0xFF, (size_t)ENTCAP * 4, stream);
    histA_kernel<8><<<gHu, blk, 0, stream>>>(up_in, cntA, M_UP_C);
    scanA(NBA_U, nblkA_U);
    fill_binned_kernel<8><<<gFu, blk, 0, stream>>>(up_in, up_out, curA, entryA,
                                                   M_UP_C, NWIN_U);
    conv_kernel<4, 0, 256><<<dim3(NWIN_U, 2), blk, 0, stream>>>(
        x, nullptr, wfU, entryA, startsA, accH, N_IN_C);
    stats_part_kernel<<<NTILES, blk, 0, stream>>>(accH, pstat);
    reduce_stats_kernel<<<64, blk, 0, stream>>>(pstat, stats);
    bn_relu_kernel<true><<<bn_blocks, blk, 0, stream>>>(accH, stats, g_up, bt_up, h16, N_OUT_C);

    // ================= stage 2: conv1 (h16 bf16 | x_skip fp32) ============
    hipMemsetAsync(accH, 0, accBytes, stream);
    hipMemsetAsync(cntA, 0, (size_t)NBA_C * 4, stream);
    hipMemsetAsync(entryA, 0xFF, (size_t)ENTCAP * 4, stream);
    histA_kernel<9><<<gHc, blk, 0, stream>>>(c1_in, cntA, M_C_C);
    scanA(NBA_C, nblkA_C);
    fill_binned_kernel<9><<<gFc, blk, 0, stream>>>(c1_in, c1_out, curA, entryA,
                                                   M_C_C, NWIN_C);
    conv_kernel<4, 1, 512><<<dim3(NWIN_C, 2), blk, 0, stream>>>(
        h16, x_skip, wf1, entryA, startsA, accH, N_OUT_C);
    stats_part_kernel<<<NTILES, blk, 0, stream>>>(accH, pstat);
    reduce_stats_kernel<<<64, blk, 0, stream>>>(pstat, stats + 64);
    bn_relu_kernel<true><<<bn_blocks, blk, 0, stream>>>(accH, stats + 64, g1, bt1, h16, N_OUT_C);

    // ================= stage 3: conv2 (h16 bf16 32ch) =====================
    hipMemsetAsync(accH, 0, accBytes, stream);
    hipMemsetAsync(cntA, 0, (size_t)NBA_C * 4, stream);
    hipMemsetAsync(entryA, 0xFF, (size_t)ENTCAP * 4, stream);
    histA_kernel<9><<<gHc, blk, 0, stream>>>(c2_in, cntA, M_C_C);
    scanA(NBA_C, nblkA_C);
    fill_binned_kernel<9><<<gFc, blk, 0, stream>>>(c2_in, c2_out, curA, entryA,
                                                   M_C_C, NWIN_C);
    conv_kernel<2, 2, 512><<<dim3(NWIN_C, 2), blk, 0, stream>>>(
        h16, nullptr, wf2, entryA, startsA, accH, N_OUT_C);
    stats_part_kernel<<<NTILES, blk, 0, stream>>>(accH, pstat);
    reduce_stats_kernel<<<64, blk, 0, stream>>>(pstat, stats + 128);
    bn_relu_kernel<false><<<bn_blocks, blk, 0, stream>>>(accH, stats + 128, g2, bt2, out, N_OUT_C);
}